// Round 1
// baseline (332.557 us; speedup 1.0000x reference)
//
#include <hip/hip_runtime.h>

#define BB 16
#define NN 512
#define NI 32
#define NHEAD 8
#define NH 512
#define NO 64
#define ROWS (BB*NN)   // 8192
#define EPSV 1e-5f
#define SLOPE 0.05f

// ---------------------------------------------------------------------------
// getV: one block per (b, tile of 32 n). x[b] staged in LDS (64 KB).
// thread t -> n_local = t>>3, h = t&7. Loops m=0..511 with 32 fp32 acc.
// ---------------------------------------------------------------------------
__global__ __launch_bounds__(256) void k_getv(const float* __restrict__ x,
                                              const float* __restrict__ Qm,
                                              float* __restrict__ V) {
    __shared__ float xs[NN * NI];   // 64 KB
    const int b = blockIdx.x;
    const int nt = blockIdx.y;
    const int t = threadIdx.x;

    const float4* xg = reinterpret_cast<const float4*>(x + (size_t)b * NN * NI);
    float4* xs4 = reinterpret_cast<float4*>(xs);
#pragma unroll
    for (int j = 0; j < (NN * NI / 4) / 256; ++j)   // 16 iters
        xs4[t + j * 256] = xg[t + j * 256];
    __syncthreads();

    const int n_l = t >> 3;
    const int h = t & 7;
    const int n = nt * 32 + n_l;

    const float q0 = Qm[h * 3 + 0], q1 = Qm[h * 3 + 1], q2 = Qm[h * 3 + 2];
    const float pn0 = xs[n * NI + 0], pn1 = xs[n * NI + 1], pn2 = xs[n * NI + 2];
    // exponent = ||(pos_n - pos_m) - Q_h||^2 = ||(pos_n - Q_h) - pos_m||^2
    const float c0 = pn0 - q0, c1 = pn1 - q1, c2 = pn2 - q2;

    float acc[NI];
#pragma unroll
    for (int i = 0; i < NI; ++i) acc[i] = 0.f;

    for (int m = 0; m < NN; ++m) {
        const float* xm = xs + m * NI;
        float t0 = c0 - xm[0];
        float t1 = c1 - xm[1];
        float t2 = c2 - xm[2];
        float e = t0 * t0 + t1 * t1 + t2 * t2;
        float D = __expf(-e);
#pragma unroll
        for (int i = 0; i < NI; ++i) acc[i] += D * xm[i];
    }
    acc[0] -= pn0; acc[1] -= pn1; acc[2] -= pn2;

    float* vout = V + ((size_t)(b * NN + n)) * (NHEAD * NI) + h * NI;
#pragma unroll
    for (int i = 0; i < NI; i += 4) {
        float4 o = make_float4(acc[i], acc[i + 1], acc[i + 2], acc[i + 3]);
        *reinterpret_cast<float4*>(vout + i) = o;
    }
}

// ---------------------------------------------------------------------------
// fp32 GEMM: C[M x NC] = A[M x K] @ W[NC x K]^T + bias. 64x64 tile, BK=16,
// 256 threads, 4x4 per thread. LDS stride 68 (16B aligned, no conflicts).
// ---------------------------------------------------------------------------
template <int K, int NC>
__global__ __launch_bounds__(256) void k_gemm(const float* __restrict__ A,
                                              const float* __restrict__ W,
                                              const float* __restrict__ bias,
                                              float* __restrict__ C) {
    constexpr int BK = 16;
    __shared__ float As[BK][68];
    __shared__ float Ws[BK][68];

    const int m0 = blockIdx.y * 64;
    const int n0 = blockIdx.x * 64;
    const int t = threadIdx.x;
    const int tx = t & 15;
    const int ty = t >> 4;
    const int lr = t >> 2;        // 0..63: row (A) / col (W) within tile
    const int lk = (t & 3) * 4;   // k quad

    float acc[4][4] = {};

    for (int k0 = 0; k0 < K; k0 += BK) {
        float4 av = *reinterpret_cast<const float4*>(&A[(size_t)(m0 + lr) * K + k0 + lk]);
        float4 wv = *reinterpret_cast<const float4*>(&W[(size_t)(n0 + lr) * K + k0 + lk]);
        __syncthreads();
        As[lk + 0][lr] = av.x; As[lk + 1][lr] = av.y;
        As[lk + 2][lr] = av.z; As[lk + 3][lr] = av.w;
        Ws[lk + 0][lr] = wv.x; Ws[lk + 1][lr] = wv.y;
        Ws[lk + 2][lr] = wv.z; Ws[lk + 3][lr] = wv.w;
        __syncthreads();
#pragma unroll
        for (int kk = 0; kk < BK; ++kk) {
            float4 a = *reinterpret_cast<const float4*>(&As[kk][ty * 4]);
            float4 w = *reinterpret_cast<const float4*>(&Ws[kk][tx * 4]);
            acc[0][0] += a.x * w.x; acc[0][1] += a.x * w.y; acc[0][2] += a.x * w.z; acc[0][3] += a.x * w.w;
            acc[1][0] += a.y * w.x; acc[1][1] += a.y * w.y; acc[1][2] += a.y * w.z; acc[1][3] += a.y * w.w;
            acc[2][0] += a.z * w.x; acc[2][1] += a.z * w.y; acc[2][2] += a.z * w.z; acc[2][3] += a.z * w.w;
            acc[3][0] += a.w * w.x; acc[3][1] += a.w * w.y; acc[3][2] += a.w * w.z; acc[3][3] += a.w * w.w;
        }
    }

    const float4 bv = *reinterpret_cast<const float4*>(&bias[n0 + tx * 4]);
#pragma unroll
    for (int i = 0; i < 4; ++i) {
        float4 o;
        o.x = acc[i][0] + bv.x;
        o.y = acc[i][1] + bv.y;
        o.z = acc[i][2] + bv.z;
        o.w = acc[i][3] + bv.w;
        *reinterpret_cast<float4*>(&C[(size_t)(m0 + ty * 4 + i) * NC + n0 + tx * 4]) = o;
    }
}

// ---------------------------------------------------------------------------
// Column sums / sumsq over rows (for BatchNorm over batch axis).
// Each block handles 64 rows; thread t owns cols t, t+256, ...
// ---------------------------------------------------------------------------
__global__ __launch_bounds__(256) void k_colstats(const float* __restrict__ Y, int C,
                                                  float* __restrict__ sums,
                                                  float* __restrict__ sumsq) {
    const int r0 = blockIdx.x * 64;
    for (int c = threadIdx.x; c < C; c += 256) {
        float s = 0.f, q = 0.f;
        for (int r = 0; r < 64; ++r) {
            float v = Y[(size_t)(r0 + r) * C + c];
            s += v;
            q += v * v;
        }
        atomicAdd(&sums[c], s);
        atomicAdd(&sumsq[c], q);
    }
}

// ---------------------------------------------------------------------------
// BN apply (+ optional leaky ReLU).
// ---------------------------------------------------------------------------
template <int C, bool LEAKY>
__global__ __launch_bounds__(256) void k_bnact(const float* __restrict__ Yin,
                                               float* __restrict__ Yout,
                                               const float* __restrict__ sums,
                                               const float* __restrict__ sumsq,
                                               const float* __restrict__ g,
                                               const float* __restrict__ bt) {
    const int total = ROWS * C;
    const float invn = 1.f / (float)ROWS;
    for (int idx = blockIdx.x * 256 + threadIdx.x; idx < total; idx += gridDim.x * 256) {
        int c = idx & (C - 1);
        float m = sums[c] * invn;
        float var = sumsq[c] * invn - m * m;
        float rs = rsqrtf(var + EPSV);
        float v = (Yin[idx] - m) * rs * g[c] + bt[c];
        if (LEAKY) v = v > 0.f ? v : SLOPE * v;
        Yout[idx] = v;
    }
}

extern "C" void kernel_launch(void* const* d_in, const int* in_sizes, int n_in,
                              void* d_out, int out_size, void* d_ws, size_t ws_size,
                              hipStream_t stream) {
    const float* x   = (const float*)d_in[0];
    const float* Q   = (const float*)d_in[1];
    const float* W1  = (const float*)d_in[2];
    const float* b1  = (const float*)d_in[3];
    const float* g1  = (const float*)d_in[4];
    const float* bt1 = (const float*)d_in[5];
    const float* W2  = (const float*)d_in[6];
    const float* b2  = (const float*)d_in[7];
    const float* g2  = (const float*)d_in[8];
    const float* bt2 = (const float*)d_in[9];
    const float* W3  = (const float*)d_in[10];
    const float* b3  = (const float*)d_in[11];
    const float* g3  = (const float*)d_in[12];
    const float* bt3 = (const float*)d_in[13];
    float* out = (float*)d_out;

    float* ws = (float*)d_ws;
    float* V  = ws;                        // 8192*256
    float* Y1 = V + (size_t)ROWS * 256;    // 8192*512
    float* Y2 = Y1 + (size_t)ROWS * 512;   // 8192*512
    float* Y3 = Y2 + (size_t)ROWS * 512;   // 8192*64
    float* st = Y3 + (size_t)ROWS * 64;    // stats: 2176 floats
    float* s1 = st;        float* q1 = s1 + 512;
    float* s2 = q1 + 512;  float* q2 = s2 + 512;
    float* s3 = q2 + 512;  float* q3 = s3 + 64;

    hipMemsetAsync(st, 0, 2176 * sizeof(float), stream);

    k_getv<<<dim3(BB, NN / 32), 256, 0, stream>>>(x, Q, V);

    k_gemm<256, 512><<<dim3(512 / 64, ROWS / 64), 256, 0, stream>>>(V, W1, b1, Y1);
    k_colstats<<<ROWS / 64, 256, 0, stream>>>(Y1, 512, s1, q1);
    k_bnact<512, true><<<2048, 256, 0, stream>>>(Y1, Y1, s1, q1, g1, bt1);

    k_gemm<512, 512><<<dim3(512 / 64, ROWS / 64), 256, 0, stream>>>(Y1, W2, b2, Y2);
    k_colstats<<<ROWS / 64, 256, 0, stream>>>(Y2, 512, s2, q2);
    k_bnact<512, true><<<2048, 256, 0, stream>>>(Y2, Y2, s2, q2, g2, bt2);

    k_gemm<512, 64><<<dim3(64 / 64, ROWS / 64), 256, 0, stream>>>(Y2, W3, b3, Y3);
    k_colstats<<<ROWS / 64, 256, 0, stream>>>(Y3, 64, s3, q3);
    k_bnact<64, false><<<1024, 256, 0, stream>>>(Y3, out, s3, q3, g3, bt3);
}

// Round 2
// 214.288 us; speedup vs baseline: 1.5519x; 1.5519x over previous
//
#include <hip/hip_runtime.h>

#define BB 16
#define NN 512
#define NI 32
#define NHEAD 8
#define NH 512
#define NO 64
#define ROWS (BB*NN)   // 8192
#define EPSV 1e-5f
#define SLOPE 0.05f

typedef __attribute__((ext_vector_type(4))) float f32x4;
typedef __attribute__((ext_vector_type(8))) short s16x8;

static __device__ __forceinline__ ushort f2bf(float f) {
    union { float f; unsigned u; } v; v.f = f;
    unsigned r = v.u + 0x7fff + ((v.u >> 16) & 1);   // RNE
    return (ushort)(r >> 16);
}

#define GLOAD_LDS16(g, l) __builtin_amdgcn_global_load_lds( \
    (const __attribute__((address_space(1))) void*)(g),     \
    (__attribute__((address_space(3))) void*)(l), 16, 0, 0)

// ---------------------------------------------------------------------------
// getV: block = (b, tile of 4 n). 256 thr: q=t&7 (m-split, lane bits 0-2),
// h=(t>>3)&7, n_l=t>>6. x staged in 128-row chunks, stride 36 (bank-clean).
// Exact shuffle-reduce over q. Writes V as bf16.
// ---------------------------------------------------------------------------
__global__ __launch_bounds__(256) void k_getv(const float* __restrict__ x,
                                              const float* __restrict__ Qm,
                                              ushort* __restrict__ Vb) {
    __shared__ float xs[128 * 36];   // 18 KB
    const int b = blockIdx.x;
    const int nt = blockIdx.y;
    const int t = threadIdx.x;
    const int q = t & 7;
    const int h = (t >> 3) & 7;
    const int n_l = t >> 6;
    const int n = nt * 4 + n_l;

    const float q0 = Qm[h * 3 + 0], q1 = Qm[h * 3 + 1], q2 = Qm[h * 3 + 2];
    const float pn0 = x[((size_t)b * NN + n) * NI + 0];
    const float pn1 = x[((size_t)b * NN + n) * NI + 1];
    const float pn2 = x[((size_t)b * NN + n) * NI + 2];
    const float c0 = pn0 - q0, c1 = pn1 - q1, c2 = pn2 - q2;

    float acc[NI];
#pragma unroll
    for (int i = 0; i < NI; ++i) acc[i] = 0.f;

    for (int c = 0; c < 4; ++c) {
        __syncthreads();
        const float4* xg = reinterpret_cast<const float4*>(x + ((size_t)b * NN + c * 128) * NI);
        float4* xs4 = reinterpret_cast<float4*>(xs);
#pragma unroll
        for (int j = 0; j < 4; ++j) {
            int e = t + j * 256;                    // float4 index, 0..1023
            xs4[(e >> 3) * 9 + (e & 7)] = xg[e];    // row*36 floats = row*9 float4
        }
        __syncthreads();
#pragma unroll
        for (int j = 0; j < 16; ++j) {
            const float* xm = xs + (j * 8 + q) * 36;
            float t0 = c0 - xm[0];
            float t1 = c1 - xm[1];
            float t2 = c2 - xm[2];
            float D = __expf(-(t0 * t0 + t1 * t1 + t2 * t2));
#pragma unroll
            for (int i = 0; i < NI; ++i) acc[i] += D * xm[i];
        }
    }

#pragma unroll
    for (int i = 0; i < NI; ++i) {
        acc[i] += __shfl_xor(acc[i], 1);
        acc[i] += __shfl_xor(acc[i], 2);
        acc[i] += __shfl_xor(acc[i], 4);
    }

    float o0 = acc[q * 4 + 0], o1 = acc[q * 4 + 1], o2 = acc[q * 4 + 2], o3 = acc[q * 4 + 3];
    if (q == 0) { o0 -= pn0; o1 -= pn1; o2 -= pn2; }
    ushort4 pk = make_ushort4(f2bf(o0), f2bf(o1), f2bf(o2), f2bf(o3));
    *reinterpret_cast<ushort4*>(Vb + ((size_t)(b * NN + n)) * (NHEAD * NI) + h * NI + q * 4) = pk;
}

// ---------------------------------------------------------------------------
// bf16 MFMA GEMM: C[M x NC] = A[M x K](bf16) @ W[NC x K](bf16)^T + bias.
// Tile 128x64, BK=32, 256 thr = 4 waves, wave w: rows [w*32, w*32+32).
// global_load_lds width 16; 2-barrier K-loop.
// ---------------------------------------------------------------------------
template <int K, int NC>
__global__ __launch_bounds__(256) void k_gemm_bf(const ushort* __restrict__ A,
                                                 const ushort* __restrict__ W,
                                                 const float* __restrict__ bias,
                                                 float* __restrict__ C) {
    __shared__ ushort As[128 * 32];  // 8 KB
    __shared__ ushort Bs[64 * 32];   // 4 KB
    const int t = threadIdx.x;
    const int lane = t & 63;
    const int w = t >> 6;
    const int m0 = blockIdx.y * 128;
    const int n0 = blockIdx.x * 64;

    const int la = lane & 15;          // fragment row/col within 16
    const int lk = (lane >> 4) * 8;    // fragment k offset
    const int sa_row = lane >> 2;      // staging: 16 rows per issue
    const int sa_col = (lane & 3) * 8;

    f32x4 acc[2][4] = {};

    for (int k0 = 0; k0 < K; k0 += 32) {
        __syncthreads();
        const ushort* ga0 = A + (size_t)(m0 + (w * 2 + 0) * 16 + sa_row) * K + k0 + sa_col;
        const ushort* ga1 = A + (size_t)(m0 + (w * 2 + 1) * 16 + sa_row) * K + k0 + sa_col;
        const ushort* gb  = W + (size_t)(n0 + w * 16 + sa_row) * K + k0 + sa_col;
        GLOAD_LDS16(ga0, &As[(w * 2 + 0) * 512]);
        GLOAD_LDS16(ga1, &As[(w * 2 + 1) * 512]);
        GLOAD_LDS16(gb,  &Bs[w * 512]);
        __syncthreads();

        s16x8 a0 = *reinterpret_cast<const s16x8*>(&As[(w * 32 + la) * 32 + lk]);
        s16x8 a1 = *reinterpret_cast<const s16x8*>(&As[(w * 32 + 16 + la) * 32 + lk]);
        s16x8 b0 = *reinterpret_cast<const s16x8*>(&Bs[(la) * 32 + lk]);
        s16x8 b1 = *reinterpret_cast<const s16x8*>(&Bs[(16 + la) * 32 + lk]);
        s16x8 b2 = *reinterpret_cast<const s16x8*>(&Bs[(32 + la) * 32 + lk]);
        s16x8 b3 = *reinterpret_cast<const s16x8*>(&Bs[(48 + la) * 32 + lk]);

        acc[0][0] = __builtin_amdgcn_mfma_f32_16x16x32_bf16(a0, b0, acc[0][0], 0, 0, 0);
        acc[0][1] = __builtin_amdgcn_mfma_f32_16x16x32_bf16(a0, b1, acc[0][1], 0, 0, 0);
        acc[0][2] = __builtin_amdgcn_mfma_f32_16x16x32_bf16(a0, b2, acc[0][2], 0, 0, 0);
        acc[0][3] = __builtin_amdgcn_mfma_f32_16x16x32_bf16(a0, b3, acc[0][3], 0, 0, 0);
        acc[1][0] = __builtin_amdgcn_mfma_f32_16x16x32_bf16(a1, b0, acc[1][0], 0, 0, 0);
        acc[1][1] = __builtin_amdgcn_mfma_f32_16x16x32_bf16(a1, b1, acc[1][1], 0, 0, 0);
        acc[1][2] = __builtin_amdgcn_mfma_f32_16x16x32_bf16(a1, b2, acc[1][2], 0, 0, 0);
        acc[1][3] = __builtin_amdgcn_mfma_f32_16x16x32_bf16(a1, b3, acc[1][3], 0, 0, 0);
    }

    float bv[4];
#pragma unroll
    for (int fn = 0; fn < 4; ++fn) bv[fn] = bias[n0 + fn * 16 + la];

#pragma unroll
    for (int fm = 0; fm < 2; ++fm)
#pragma unroll
        for (int fn = 0; fn < 4; ++fn)
#pragma unroll
            for (int r = 0; r < 4; ++r) {
                int row = m0 + w * 32 + fm * 16 + (lane >> 4) * 4 + r;
                int col = n0 + fn * 16 + la;
                C[(size_t)row * NC + col] = acc[fm][fn][r] + bv[fn];
            }
}

// ---------------------------------------------------------------------------
// Column sums / sumsq over rows (BatchNorm stats).
// ---------------------------------------------------------------------------
__global__ __launch_bounds__(256) void k_colstats(const float* __restrict__ Y, int C,
                                                  float* __restrict__ sums,
                                                  float* __restrict__ sumsq) {
    const int r0 = blockIdx.x * 64;
    for (int c = threadIdx.x; c < C; c += 256) {
        float s = 0.f, q = 0.f;
        for (int r = 0; r < 64; ++r) {
            float v = Y[(size_t)(r0 + r) * C + c];
            s += v;
            q += v * v;
        }
        atomicAdd(&sums[c], s);
        atomicAdd(&sumsq[c], q);
    }
}

// ---------------------------------------------------------------------------
// BN apply + leaky ReLU, bf16 output (feeds next bf16 GEMM).
// ---------------------------------------------------------------------------
template <int C>
__global__ __launch_bounds__(256) void k_bnact_bf(const float* __restrict__ Yin,
                                                  ushort* __restrict__ Yout,
                                                  const float* __restrict__ sums,
                                                  const float* __restrict__ sumsq,
                                                  const float* __restrict__ g,
                                                  const float* __restrict__ bt) {
    const int total4 = ROWS * C / 4;
    const float invn = 1.f / (float)ROWS;
    for (int e = blockIdx.x * 256 + threadIdx.x; e < total4; e += gridDim.x * 256) {
        int c0 = (e * 4) & (C - 1);
        float4 v = reinterpret_cast<const float4*>(Yin)[e];
        float vv[4] = {v.x, v.y, v.z, v.w};
        ushort oo[4];
#pragma unroll
        for (int j = 0; j < 4; ++j) {
            int c = c0 + j;
            float m = sums[c] * invn;
            float var = sumsq[c] * invn - m * m;
            float rs = rsqrtf(var + EPSV);
            float val = (vv[j] - m) * rs * g[c] + bt[c];
            val = val > 0.f ? val : SLOPE * val;
            oo[j] = f2bf(val);
        }
        *reinterpret_cast<ushort4*>(Yout + (size_t)e * 4) = make_ushort4(oo[0], oo[1], oo[2], oo[3]);
    }
}

// Final BN (no activation), fp32 output.
template <int C>
__global__ __launch_bounds__(256) void k_bn_f32(const float* __restrict__ Yin,
                                                float* __restrict__ Yout,
                                                const float* __restrict__ sums,
                                                const float* __restrict__ sumsq,
                                                const float* __restrict__ g,
                                                const float* __restrict__ bt) {
    const int total = ROWS * C;
    const float invn = 1.f / (float)ROWS;
    for (int idx = blockIdx.x * 256 + threadIdx.x; idx < total; idx += gridDim.x * 256) {
        int c = idx & (C - 1);
        float m = sums[c] * invn;
        float var = sumsq[c] * invn - m * m;
        float rs = rsqrtf(var + EPSV);
        Yout[idx] = (Yin[idx] - m) * rs * g[c] + bt[c];
    }
}

// ---------------------------------------------------------------------------
// Convert W1/W2/W3 to bf16 (float4 -> ushort4).
// ---------------------------------------------------------------------------
__global__ __launch_bounds__(256) void k_wconv(const float* __restrict__ W1f,
                                               const float* __restrict__ W2f,
                                               const float* __restrict__ W3f,
                                               ushort* __restrict__ W1b,
                                               ushort* __restrict__ W2b,
                                               ushort* __restrict__ W3b) {
    int i = blockIdx.x * 256 + threadIdx.x;  // float4 index
    if (i < 32768) {
        float4 v = reinterpret_cast<const float4*>(W1f)[i];
        *reinterpret_cast<ushort4*>(W1b + (size_t)i * 4) =
            make_ushort4(f2bf(v.x), f2bf(v.y), f2bf(v.z), f2bf(v.w));
    }
    if (i < 65536) {
        float4 v = reinterpret_cast<const float4*>(W2f)[i];
        *reinterpret_cast<ushort4*>(W2b + (size_t)i * 4) =
            make_ushort4(f2bf(v.x), f2bf(v.y), f2bf(v.z), f2bf(v.w));
    }
    if (i < 8192) {
        float4 v = reinterpret_cast<const float4*>(W3f)[i];
        *reinterpret_cast<ushort4*>(W3b + (size_t)i * 4) =
            make_ushort4(f2bf(v.x), f2bf(v.y), f2bf(v.z), f2bf(v.w));
    }
}

extern "C" void kernel_launch(void* const* d_in, const int* in_sizes, int n_in,
                              void* d_out, int out_size, void* d_ws, size_t ws_size,
                              hipStream_t stream) {
    const float* x   = (const float*)d_in[0];
    const float* Q   = (const float*)d_in[1];
    const float* W1  = (const float*)d_in[2];
    const float* b1  = (const float*)d_in[3];
    const float* g1  = (const float*)d_in[4];
    const float* bt1 = (const float*)d_in[5];
    const float* W2  = (const float*)d_in[6];
    const float* b2  = (const float*)d_in[7];
    const float* g2  = (const float*)d_in[8];
    const float* bt2 = (const float*)d_in[9];
    const float* W3  = (const float*)d_in[10];
    const float* b3  = (const float*)d_in[11];
    const float* g3  = (const float*)d_in[12];
    const float* bt3 = (const float*)d_in[13];
    float* out = (float*)d_out;

    // Workspace layout (aliased; ~29 MB total):
    //  [0, 16MB)              Yf    : fp32 8192x512, reused for Y1, Y2, Y3
    //  [16MB, +4MB)           Vb    : bf16 8192x256      (dead after gemm1)
    //  [20MB, +8MB)           Y1b   : bf16 8192x512      (dead after gemm2)
    //  [16MB, +8MB)           Y2b   : bf16 8192x512      (overlaps Vb+Y1b[0:4MB), both dead)
    //  [28MB, ...)            W1b(256KB) W2b(512KB) W3b(64KB) stats(8.5KB)
    char* wsb = (char*)d_ws;
    float*  Yf  = (float*)wsb;
    ushort* Vb  = (ushort*)(wsb + (16u << 20));
    ushort* Y1b = (ushort*)(wsb + (20u << 20));
    ushort* Y2b = (ushort*)(wsb + (16u << 20));
    ushort* W1b = (ushort*)(wsb + (28u << 20));
    ushort* W2b = W1b + 512 * 256;
    ushort* W3b = W2b + 512 * 512;
    float*  st  = (float*)(W3b + 64 * 512);
    float* s1 = st;        float* q1 = s1 + 512;
    float* s2 = q1 + 512;  float* q2 = s2 + 512;
    float* s3 = q2 + 512;  float* q3 = s3 + 64;

    hipMemsetAsync(st, 0, 2176 * sizeof(float), stream);

    k_wconv<<<256, 256, 0, stream>>>(W1, W2, W3, W1b, W2b, W3b);
    k_getv<<<dim3(BB, NN / 4), 256, 0, stream>>>(x, Q, Vb);

    // layer 1: K=256, NC=512
    k_gemm_bf<256, 512><<<dim3(512 / 64, ROWS / 128), 256, 0, stream>>>(Vb, W1b, b1, Yf);
    k_colstats<<<ROWS / 64, 256, 0, stream>>>(Yf, 512, s1, q1);
    k_bnact_bf<512><<<1024, 256, 0, stream>>>(Yf, Y1b, s1, q1, g1, bt1);

    // layer 2: K=512, NC=512
    k_gemm_bf<512, 512><<<dim3(512 / 64, ROWS / 128), 256, 0, stream>>>(Y1b, W2b, b2, Yf);
    k_colstats<<<ROWS / 64, 256, 0, stream>>>(Yf, 512, s2, q2);
    k_bnact_bf<512><<<1024, 256, 0, stream>>>(Yf, Y2b, s2, q2, g2, bt2);

    // layer 3: K=512, NC=64
    k_gemm_bf<512, 64><<<dim3(64 / 64, ROWS / 128), 256, 0, stream>>>(Y2b, W3b, b3, Yf);
    k_colstats<<<ROWS / 64, 256, 0, stream>>>(Yf, 64, s3, q3);
    k_bn_f32<64><<<512, 256, 0, stream>>>(Yf, out, s3, q3, g3, bt3);
}

// Round 3
// 166.659 us; speedup vs baseline: 1.9954x; 1.2858x over previous
//
#include <hip/hip_runtime.h>

#define BB 16
#define NN 512
#define NI 32
#define NHEAD 8
#define NH 512
#define NO 64
#define ROWS (BB*NN)   // 8192
#define EPSV 1e-5f
#define SLOPE 0.05f

typedef __attribute__((ext_vector_type(4))) float f32x4;
typedef __attribute__((ext_vector_type(8))) short s16x8;

static __device__ __forceinline__ ushort f2bf(float f) {
    union { float f; unsigned u; } v; v.f = f;
    unsigned r = v.u + 0x7fff + ((v.u >> 16) & 1);   // RNE
    return (ushort)(r >> 16);
}

static __device__ __forceinline__ unsigned cvt_pk_bf16(float lo, float hi) {
    unsigned r;
    asm("v_cvt_pk_bf16_f32 %0, %1, %2" : "=v"(r) : "v"(lo), "v"(hi));
    return r;
}

#define GLOAD_LDS16(g, l) __builtin_amdgcn_global_load_lds( \
    (const __attribute__((address_space(1))) void*)(g),     \
    (__attribute__((address_space(3))) void*)(l), 16, 0, 0)

// ---------------------------------------------------------------------------
// getV via MFMA. Block: (b, tile of 64 hn-rows), 4 waves x 16 rows.
// D fragments computed in-register (exp), A-operand from VGPRs;
// x^T staged once in LDS as bf16 (XOR-swizzled); B-operand = x^T.
// C frag: col=lane&15 (=i), row=(lane>>4)*4+r (=n within wave's 16 rows).
// ---------------------------------------------------------------------------
#define XTI(i, m) ((((i) * 512) + (m)) ^ (((i) & 7) << 3))

__global__ __launch_bounds__(256) void k_getv(const float* __restrict__ x,
                                              const float* __restrict__ Qm,
                                              ushort* __restrict__ Vb) {
    __shared__ ushort xT[32 * 512];   // 32 KB, swizzled
    __shared__ float4 poss[NN];       // 8 KB
    const int b = blockIdx.x;
    const int tile = blockIdx.y;          // 0..63
    const int h = tile >> 3;              // uniform per block
    const int nb = (tile & 7) * 64;
    const int t = threadIdx.x;
    const int lane = t & 63;
    const int w = t >> 6;

    const float4* xg = reinterpret_cast<const float4*>(x + (size_t)b * NN * NI);
#pragma unroll
    for (int j = 0; j < 16; ++j) {
        int e = t + j * 256;              // float4 index, 0..4095
        int m = e >> 3, i4 = e & 7;
        float4 v = xg[e];
        unsigned p01 = cvt_pk_bf16(v.x, v.y);
        unsigned p23 = cvt_pk_bf16(v.z, v.w);
        xT[XTI(i4 * 4 + 0, m)] = (ushort)(p01 & 0xffff);
        xT[XTI(i4 * 4 + 1, m)] = (ushort)(p01 >> 16);
        xT[XTI(i4 * 4 + 2, m)] = (ushort)(p23 & 0xffff);
        xT[XTI(i4 * 4 + 3, m)] = (ushort)(p23 >> 16);
        if (i4 == 0) poss[m] = v;
    }
    __syncthreads();

    const int la = lane & 15;
    const int mko = (lane >> 4) * 8;
    const float qx = Qm[h * 3 + 0], qy = Qm[h * 3 + 1], qz = Qm[h * 3 + 2];
    const int n_a = nb + w * 16 + la;     // A-fragment row (n)
    float4 pa = poss[n_a];
    const float c0 = pa.x - qx, c1 = pa.y - qy, c2 = pa.z - qz;

    f32x4 acc0 = {0.f, 0.f, 0.f, 0.f}, acc1 = {0.f, 0.f, 0.f, 0.f};

    for (int mc = 0; mc < NN; mc += 32) {
        float d[8];
#pragma unroll
        for (int j = 0; j < 8; ++j) {
            float4 pm = poss[mc + mko + j];
            float t0 = c0 - pm.x, t1 = c1 - pm.y, t2 = c2 - pm.z;
            float e = fmaf(t0, t0, fmaf(t1, t1, t2 * t2));
            d[j] = exp2f(e * -1.4426950408889634f);
        }
        union { s16x8 v; unsigned u[4]; } af;
#pragma unroll
        for (int j = 0; j < 4; ++j) af.u[j] = cvt_pk_bf16(d[2 * j], d[2 * j + 1]);
        s16x8 b0 = *reinterpret_cast<const s16x8*>(&xT[XTI(la, mc + mko)]);
        s16x8 b1 = *reinterpret_cast<const s16x8*>(&xT[XTI(la + 16, mc + mko)]);
        acc0 = __builtin_amdgcn_mfma_f32_16x16x32_bf16(af.v, b0, acc0, 0, 0, 0);
        acc1 = __builtin_amdgcn_mfma_f32_16x16x32_bf16(af.v, b1, acc1, 0, 0, 0);
    }

    const int i = la;
#pragma unroll
    for (int r = 0; r < 4; ++r) {
        int n = nb + w * 16 + (lane >> 4) * 4 + r;
        float v0 = acc0[r], v1 = acc1[r];
        if (i < 3) {
            float4 p = poss[n];
            v0 -= (i == 0) ? p.x : (i == 1) ? p.y : p.z;
        }
        ushort* vp = Vb + (((size_t)(b * NN + n)) * NHEAD + h) * NI;
        vp[i] = f2bf(v0);
        vp[i + 16] = f2bf(v1);
    }
}

// ---------------------------------------------------------------------------
// bf16 MFMA GEMM + fused BN column stats.
// C[M x NC] = A[M x K](bf16) @ W[NC x K](bf16)^T + bias (fp32 out).
// Tile BM x 64, BK=32, 256 thr = 4 waves; 2-phase double-buffered pipeline
// (T3 minimum: STAGE next before ds_read+MFMA, one barrier per step).
// Epilogue: per-column sum/sumsq -> shfl reduce -> LDS -> global atomics.
// ---------------------------------------------------------------------------
template <int K, int NC, int BM>
__global__ __launch_bounds__(256) void k_gemm_bf(const ushort* __restrict__ A,
                                                 const ushort* __restrict__ W,
                                                 const float* __restrict__ bias,
                                                 float* __restrict__ C,
                                                 float* __restrict__ sums,
                                                 float* __restrict__ sumsq) {
    constexpr int KSTEPS = K / 32;
    constexpr int FM = BM / 64;          // 128 -> 2, 64 -> 1
    __shared__ ushort As[2][BM * 32];
    __shared__ ushort Bs[2][64 * 32];
    __shared__ float red[2][64];

    const int t = threadIdx.x;
    const int lane = t & 63;
    const int w = t >> 6;
    const int m0 = blockIdx.y * BM;
    const int n0 = blockIdx.x * 64;
    const int la = lane & 15;
    const int lk = (lane >> 4) * 8;
    const int srow = t >> 2;
    const int scol = (t & 3) * 8;

    if (t < 64) { red[0][t] = 0.f; red[1][t] = 0.f; }

    auto STAGE = [&](int buf, int k0) {
        GLOAD_LDS16(A + (size_t)(m0 + srow) * K + k0 + scol, &As[buf][t * 8]);
        if (FM == 2)
            GLOAD_LDS16(A + (size_t)(m0 + 64 + srow) * K + k0 + scol, &As[buf][2048 + t * 8]);
        GLOAD_LDS16(W + (size_t)(n0 + srow) * K + k0 + scol, &Bs[buf][t * 8]);
    };

    f32x4 acc[FM][4];
#pragma unroll
    for (int fm = 0; fm < FM; ++fm)
#pragma unroll
        for (int fn = 0; fn < 4; ++fn) acc[fm][fn] = (f32x4){0.f, 0.f, 0.f, 0.f};

    STAGE(0, 0);
    __syncthreads();

    int cur = 0;
    for (int ks = 0; ks < KSTEPS; ++ks) {
        if (ks + 1 < KSTEPS) STAGE(cur ^ 1, (ks + 1) * 32);
        s16x8 b0 = *reinterpret_cast<const s16x8*>(&Bs[cur][(0 + la) * 32 + lk]);
        s16x8 b1 = *reinterpret_cast<const s16x8*>(&Bs[cur][(16 + la) * 32 + lk]);
        s16x8 b2 = *reinterpret_cast<const s16x8*>(&Bs[cur][(32 + la) * 32 + lk]);
        s16x8 b3 = *reinterpret_cast<const s16x8*>(&Bs[cur][(48 + la) * 32 + lk]);
#pragma unroll
        for (int fm = 0; fm < FM; ++fm) {
            s16x8 a = *reinterpret_cast<const s16x8*>(&As[cur][(w * 16 * FM + fm * 16 + la) * 32 + lk]);
            acc[fm][0] = __builtin_amdgcn_mfma_f32_16x16x32_bf16(a, b0, acc[fm][0], 0, 0, 0);
            acc[fm][1] = __builtin_amdgcn_mfma_f32_16x16x32_bf16(a, b1, acc[fm][1], 0, 0, 0);
            acc[fm][2] = __builtin_amdgcn_mfma_f32_16x16x32_bf16(a, b2, acc[fm][2], 0, 0, 0);
            acc[fm][3] = __builtin_amdgcn_mfma_f32_16x16x32_bf16(a, b3, acc[fm][3], 0, 0, 0);
        }
        __syncthreads();
        cur ^= 1;
    }

    float bv[4], s[4] = {}, q[4] = {};
#pragma unroll
    for (int fn = 0; fn < 4; ++fn) bv[fn] = bias[n0 + fn * 16 + la];

#pragma unroll
    for (int fm = 0; fm < FM; ++fm)
#pragma unroll
        for (int fn = 0; fn < 4; ++fn)
#pragma unroll
            for (int r = 0; r < 4; ++r) {
                int row = m0 + w * 16 * FM + fm * 16 + (lane >> 4) * 4 + r;
                float v = acc[fm][fn][r] + bv[fn];
                C[(size_t)row * NC + n0 + fn * 16 + la] = v;
                s[fn] += v; q[fn] += v * v;
            }
#pragma unroll
    for (int fn = 0; fn < 4; ++fn) {
        s[fn] += __shfl_xor(s[fn], 16); s[fn] += __shfl_xor(s[fn], 32);
        q[fn] += __shfl_xor(q[fn], 16); q[fn] += __shfl_xor(q[fn], 32);
    }
    if (lane < 16) {
#pragma unroll
        for (int fn = 0; fn < 4; ++fn) {
            atomicAdd(&red[0][fn * 16 + lane], s[fn]);
            atomicAdd(&red[1][fn * 16 + lane], q[fn]);
        }
    }
    __syncthreads();
    if (t < 64) {
        atomicAdd(&sums[n0 + t], red[0][t]);
        atomicAdd(&sumsq[n0 + t], red[1][t]);
    }
}

// ---------------------------------------------------------------------------
// BN apply + leaky ReLU, bf16 output.
// ---------------------------------------------------------------------------
template <int C>
__global__ __launch_bounds__(256) void k_bnact_bf(const float* __restrict__ Yin,
                                                  ushort* __restrict__ Yout,
                                                  const float* __restrict__ sums,
                                                  const float* __restrict__ sumsq,
                                                  const float* __restrict__ g,
                                                  const float* __restrict__ bt) {
    const int total4 = ROWS * C / 4;
    const float invn = 1.f / (float)ROWS;
    for (int e = blockIdx.x * 256 + threadIdx.x; e < total4; e += gridDim.x * 256) {
        int c0 = (e * 4) & (C - 1);
        float4 v = reinterpret_cast<const float4*>(Yin)[e];
        float vv[4] = {v.x, v.y, v.z, v.w};
        ushort oo[4];
#pragma unroll
        for (int j = 0; j < 4; ++j) {
            int c = c0 + j;
            float m = sums[c] * invn;
            float var = sumsq[c] * invn - m * m;
            float rs = rsqrtf(var + EPSV);
            float val = (vv[j] - m) * rs * g[c] + bt[c];
            val = val > 0.f ? val : SLOPE * val;
            oo[j] = f2bf(val);
        }
        *reinterpret_cast<ushort4*>(Yout + (size_t)e * 4) = make_ushort4(oo[0], oo[1], oo[2], oo[3]);
    }
}

// Final BN (no activation), fp32 output.
template <int C>
__global__ __launch_bounds__(256) void k_bn_f32(const float* __restrict__ Yin,
                                                float* __restrict__ Yout,
                                                const float* __restrict__ sums,
                                                const float* __restrict__ sumsq,
                                                const float* __restrict__ g,
                                                const float* __restrict__ bt) {
    const int total = ROWS * C;
    const float invn = 1.f / (float)ROWS;
    for (int idx = blockIdx.x * 256 + threadIdx.x; idx < total; idx += gridDim.x * 256) {
        int c = idx & (C - 1);
        float m = sums[c] * invn;
        float var = sumsq[c] * invn - m * m;
        float rs = rsqrtf(var + EPSV);
        Yout[idx] = (Yin[idx] - m) * rs * g[c] + bt[c];
    }
}

// ---------------------------------------------------------------------------
// Convert W1/W2/W3 to bf16.
// ---------------------------------------------------------------------------
__global__ __launch_bounds__(256) void k_wconv(const float* __restrict__ W1f,
                                               const float* __restrict__ W2f,
                                               const float* __restrict__ W3f,
                                               ushort* __restrict__ W1b,
                                               ushort* __restrict__ W2b,
                                               ushort* __restrict__ W3b) {
    int i = blockIdx.x * 256 + threadIdx.x;  // float4 index
    if (i < 32768) {
        float4 v = reinterpret_cast<const float4*>(W1f)[i];
        *reinterpret_cast<ushort4*>(W1b + (size_t)i * 4) =
            make_ushort4(f2bf(v.x), f2bf(v.y), f2bf(v.z), f2bf(v.w));
    }
    if (i < 65536) {
        float4 v = reinterpret_cast<const float4*>(W2f)[i];
        *reinterpret_cast<ushort4*>(W2b + (size_t)i * 4) =
            make_ushort4(f2bf(v.x), f2bf(v.y), f2bf(v.z), f2bf(v.w));
    }
    if (i < 8192) {
        float4 v = reinterpret_cast<const float4*>(W3f)[i];
        *reinterpret_cast<ushort4*>(W3b + (size_t)i * 4) =
            make_ushort4(f2bf(v.x), f2bf(v.y), f2bf(v.z), f2bf(v.w));
    }
}

extern "C" void kernel_launch(void* const* d_in, const int* in_sizes, int n_in,
                              void* d_out, int out_size, void* d_ws, size_t ws_size,
                              hipStream_t stream) {
    const float* x   = (const float*)d_in[0];
    const float* Q   = (const float*)d_in[1];
    const float* W1  = (const float*)d_in[2];
    const float* b1  = (const float*)d_in[3];
    const float* g1  = (const float*)d_in[4];
    const float* bt1 = (const float*)d_in[5];
    const float* W2  = (const float*)d_in[6];
    const float* b2  = (const float*)d_in[7];
    const float* g2  = (const float*)d_in[8];
    const float* bt2 = (const float*)d_in[9];
    const float* W3  = (const float*)d_in[10];
    const float* b3  = (const float*)d_in[11];
    const float* g3  = (const float*)d_in[12];
    const float* bt3 = (const float*)d_in[13];
    float* out = (float*)d_out;

    char* wsb = (char*)d_ws;
    float*  Yf  = (float*)wsb;                       // fp32 8192x512 (reused)
    ushort* Vb  = (ushort*)(wsb + (16u << 20));      // bf16 8192x256
    ushort* Y1b = (ushort*)(wsb + (20u << 20));      // bf16 8192x512
    ushort* Y2b = (ushort*)(wsb + (16u << 20));      // bf16 8192x512 (aliases Vb)
    ushort* W1b = (ushort*)(wsb + (28u << 20));
    ushort* W2b = W1b + 512 * 256;
    ushort* W3b = W2b + 512 * 512;
    float*  st  = (float*)(W3b + 64 * 512);
    float* s1 = st;        float* q1 = s1 + 512;
    float* s2 = q1 + 512;  float* q2 = s2 + 512;
    float* s3 = q2 + 512;  float* q3 = s3 + 64;

    hipMemsetAsync(st, 0, 2176 * sizeof(float), stream);

    k_wconv<<<256, 256, 0, stream>>>(W1, W2, W3, W1b, W2b, W3b);
    k_getv<<<dim3(BB, 64), 256, 0, stream>>>(x, Q, Vb);

    // layer 1: K=256, NC=512, BM=128 -> grid (8, 64)
    k_gemm_bf<256, 512, 128><<<dim3(8, 64), 256, 0, stream>>>(Vb, W1b, b1, Yf, s1, q1);
    k_bnact_bf<512><<<1024, 256, 0, stream>>>(Yf, Y1b, s1, q1, g1, bt1);

    // layer 2: K=512, NC=512, BM=128
    k_gemm_bf<512, 512, 128><<<dim3(8, 64), 256, 0, stream>>>(Y1b, W2b, b2, Yf, s2, q2);
    k_bnact_bf<512><<<1024, 256, 0, stream>>>(Yf, Y2b, s2, q2, g2, bt2);

    // layer 3: K=512, NC=64, BM=64 -> grid (1, 128)
    k_gemm_bf<512, 64, 64><<<dim3(1, 128), 256, 0, stream>>>(Y2b, W3b, b3, Yf, s3, q3);
    k_bn_f32<64><<<512, 256, 0, stream>>>(Yf, out, s3, q3, g3, bt3);
}